// Round 6
// baseline (245.353 us; speedup 1.0000x reference)
//
#include <hip/hip_runtime.h>
#include <math.h>

#define B_   2
#define P_   200000
#define Q_   100
#define NBLK 3125        // P_/64 blocks per batch in pass1

// ws byte layout:
//   [0, 100000)        ulonglong2 flags[B_][NBLK]  (per-block 100-bit bitmap,
//                       plain-stored unconditionally -> no zeroing, no atomics)
//   [102400, 103200)   float msc[B_*Q_]            (prep)
//   [103424, 104224)   int   seg[B_*Q_]            (pass2)
//
// d_out (float): [0,B*P) sem | [B*P,2BP) ins | [2BP,3BP) max_confs
// pass1 stashes mid (float, -1 invalid) in ins slot; pass3 finalizes.

__global__ void pano_prep(const float* __restrict__ logits,
                          float* __restrict__ msc)
{
    const int b = blockIdx.x, tid = threadIdx.x;
    if (tid < Q_) {
        float l0 = logits[(b * Q_ + tid) * 2 + 0];
        float l1 = logits[(b * Q_ + tid) * 2 + 1];
        // keep iff argmax==0 iff !(l1>l0) (jnp first-index tie rule)
        msc[b * Q_ + tid] = (l1 > l0) ? -1e30f : fmaxf(l0, l1);
    }
}

// 4 lanes/row, 16 rows/wave, 64 rows per 256-thread block. P_ = 3125*64.
__global__ __launch_bounds__(256) void pano_pass1(
    const float* __restrict__ masks,         // [B,P,Q]
    const unsigned char* __restrict__ pad,   // [B,P]
    float* __restrict__ out,                 // [3,B,P]
    const float* __restrict__ msc,           // [B,Q] ws
    ulonglong2* __restrict__ flags)          // [B][NBLK] ws
{
    const int b = blockIdx.y, tid = threadIdx.x;
    __shared__ float s_msc[Q_];
    __shared__ int   s_flag[Q_];
    if (tid < Q_) { s_msc[tid] = msc[b * Q_ + tid]; s_flag[tid] = 0; }
    __syncthreads();

    const int wave = tid >> 6, wl = tid & 63;
    const int g = wl >> 2, l = wl & 3;
    const int p = blockIdx.x * 64 + wave * 16 + g;

    const float* rowp = masks + ((size_t)b * P_ + p) * Q_;
    const float4* grow = reinterpret_cast<const float4*>(rowp);

    // 7 independent 16B loads per lane -> high MLP
    float4 v[7];
    #pragma unroll
    for (int k = 0; k < 6; ++k) v[k] = grow[k * 4 + l];
    v[6] = grow[24];                 // same addr all 4 lanes; only l==0 consumes

    float S0 = 0.0f;
    float v1 = -INFINITY, v2 = -INFINITY, m1 = 0.0f;
    int   q1 = -1;

    #pragma unroll
    for (int k = 0; k < 7; ++k) {
        const bool act = (k < 6) || (l == 0);
        const int  qb  = (k < 6) ? (16 * k + 4 * l) : 96;
        float xv[4] = {v[k].x, v[k].y, v[k].z, v[k].w};
        #pragma unroll
        for (int e = 0; e < 4; ++e) {
            int q = qb + e;
            // FAST path: v_exp + v_rcp sigmoid (error ~1e-6 rel)
            float m   = __builtin_amdgcn_rcpf(1.0f + __expf(-xv[e]));
            float val = act ? s_msc[q] * m : -INFINITY;  // ghost: exp->0, never wins
            S0 += __expf(val);                           // vals bounded ~[0,4]
            bool t = val > v1;                           // strict: first-max tie
            v2 = t ? v1 : fmaxf(v2, val);
            v1 = t ? val : v1;
            m1 = t ? m   : m1;
            q1 = t ? q   : q1;
        }
    }

    // merge 4 lanes (xor 1,2); v1 tie -> smaller q (unsigned: -1 loses)
    #pragma unroll
    for (int off = 1; off <= 2; off <<= 1) {
        float So  = __shfl_xor(S0, off, 64);
        float v1o = __shfl_xor(v1, off, 64);
        float v2o = __shfl_xor(v2, off, 64);
        float m1o = __shfl_xor(m1, off, 64);
        int   q1o = __shfl_xor(q1, off, 64);
        S0 += So;
        bool t = (v1o > v1) || (v1o == v1 && (unsigned)q1o < (unsigned)q1);
        v2 = fmaxf(fminf(v1, v1o), fmaxf(v2, v2o));      // 2nd max of union
        v1 = t ? v1o : v1;
        m1 = t ? m1o : m1;
        q1 = t ? q1o : q1;
    }

    // EXACT fallback when fast top-2 gap can't certify argmax (~0.06% rows):
    // bit-identical chain to the validated R2 kernel (expf + IEEE div).
    if (l == 0 && (v1 - v2) < 5e-5f) {
        float bv = -INFINITY, bm = 0.0f; int bq = -1;
        for (int q = 0; q < Q_; ++q) {
            float x = rowp[q];                 // L1-hot
            float e = expf(-x);
            float m = 1.0f / (1.0f + e);
            float vv = s_msc[q] * m;
            if (vv > bv) { bv = vv; bq = q; bm = m; }
        }
        q1 = bq; m1 = bm;                      // v1/S0 keep fast values (2% tol)
    }

    bool valid = (q1 >= 0) && (s_msc[q1] > -1e29f) &&     // keep[mid]
                 (m1 >= 1e-3f) &&
                 (pad[(size_t)b * P_ + p] == 0);

    float conf = __expf(v1) * __builtin_amdgcn_rcpf(S0);  // 2% tol
    float insf = valid ? (float)q1 : -1.0f;
    if (l == 0 && valid) s_flag[q1] = 1;                  // benign LDS race

    // compact stores: lane t<16 gathers row t's result from its leader lane 4t
    int   src    = (wl & 15) * 4;
    float conf_g = __shfl(conf, src, 64);
    float insf_g = __shfl(insf, src, 64);
    if (wl < 16) {
        int prow = blockIdx.x * 64 + wave * 16 + wl;
        size_t o = (size_t)b * P_ + prow;
        out[o]                       = 0.0f;   // sem: labels[mid]==0 whenever valid
        out[(size_t)B_ * P_ + o]     = insf_g;
        out[2 * (size_t)B_ * P_ + o] = conf_g;
    }

    __syncthreads();
    // per-block 100-bit bitmap via two wave ballots; plain stores, no atomics.
    // wave0 ballot -> bits 0..63 (tid), wave1 ballot -> bits 0..35 (tid-64);
    // tid 100..127 contribute 0. Every block writes its own slot -> no init.
    {
        bool f = (tid < Q_) ? (s_flag[tid] != 0) : false;
        unsigned long long m = __ballot(f);
        if (tid == 0)  flags[b * NBLK + blockIdx.x].x = m;
        if (tid == 64) flags[b * NBLK + blockIdx.x].y = m;
    }
}

// OR-reduce 3125 bitmaps per batch + cumsum -> seg[b][q]
__global__ __launch_bounds__(256) void pano_pass2(
    const ulonglong2* __restrict__ flags,
    int* __restrict__ seg)
{
    const int b = blockIdx.x, tid = threadIdx.x;
    unsigned long long m0 = 0ull, m1 = 0ull;
    for (int i = tid; i < NBLK; i += 256) {
        ulonglong2 w = flags[b * NBLK + i];
        m0 |= w.x; m1 |= w.y;
    }
    #pragma unroll
    for (int off = 32; off; off >>= 1) {
        m0 |= __shfl_xor(m0, off, 64);
        m1 |= __shfl_xor(m1, off, 64);
    }
    __shared__ unsigned long long sm0[4], sm1[4];
    if ((tid & 63) == 0) { sm0[tid >> 6] = m0; sm1[tid >> 6] = m1; }
    __syncthreads();
    if (tid == 0) {
        m0 = sm0[0] | sm0[1] | sm0[2] | sm0[3];
        m1 = sm1[0] | sm1[1] | sm1[2] | sm1[3];
        int c = 0;
        for (int q = 0; q < Q_; ++q) {
            c += (int)((q < 64 ? (m0 >> q) : (m1 >> (q - 64))) & 1ull);
            seg[b * Q_ + q] = c;    // inclusive cumsum of nonempty
        }
    }
}

__global__ __launch_bounds__(256) void pano_pass3(
    const int* __restrict__ seg,
    float* __restrict__ out)
{
    const int b = blockIdx.y, tid = threadIdx.x;
    __shared__ int s_seg[Q_];
    if (tid < Q_) s_seg[tid] = seg[b * Q_ + tid];
    __syncthreads();

    int p = blockIdx.x * blockDim.x + tid;
    if (p < P_) {
        size_t o = (size_t)B_ * P_ + (size_t)b * P_ + p;
        float f = out[o];
        out[o] = (f >= 0.0f) ? (float)s_seg[(int)f] : 0.0f;
    }
}

extern "C" void kernel_launch(void* const* d_in, const int* in_sizes, int n_in,
                              void* d_out, int out_size, void* d_ws, size_t ws_size,
                              hipStream_t stream) {
    const float* logits = (const float*)d_in[0];
    const float* masks  = (const float*)d_in[1];
    const unsigned char* pad = (const unsigned char*)d_in[2];
    float* out = (float*)d_out;

    ulonglong2* flags = (ulonglong2*)d_ws;                 // [B][NBLK]
    float*      mscp  = (float*)((char*)d_ws + 102400);    // [B*Q_]
    int*        seg   = (int*)((char*)d_ws + 103424);      // [B*Q_]

    pano_prep<<<dim3(B_), dim3(128), 0, stream>>>(logits, mscp);

    dim3 block(256);
    pano_pass1<<<dim3(NBLK, B_), block, 0, stream>>>(masks, pad, out, mscp, flags);
    pano_pass2<<<dim3(B_), block, 0, stream>>>(flags, seg);
    pano_pass3<<<dim3((P_ + 255) / 256, B_), block, 0, stream>>>(seg, out);
}